// Round 8
// baseline (528.450 us; speedup 1.0000x reference)
//
#include <hip/hip_runtime.h>
#include <math.h>

#define BB   4
#define LL   2048
#define DM   256
#define DI   512
#define DSN  16
#define HIDN 512
#define NC   64
#define CK   32           // LL / NC
#define ROWS (BB*LL)      // 8192

typedef __attribute__((ext_vector_type(8))) short s8v;   // 8 bf16 (4 VGPRs)
typedef __attribute__((ext_vector_type(4))) float f4v;   // 4 fp32 acc

__device__ __forceinline__ float sig_(float x) { return 1.f / (1.f + __expf(-x)); }
__device__ __forceinline__ float dot4(float4 a, float4 w, float acc) {
    return fmaf(a.x,w.x, fmaf(a.y,w.y, fmaf(a.z,w.z, fmaf(a.w,w.w, acc))));
}
__device__ __forceinline__ unsigned short rne_bf16(float f) {
    union { float f; unsigned u; } v; v.f = f;
    unsigned r = v.u + 0x7FFFu + ((v.u >> 16) & 1u);
    return (unsigned short)(r >> 16);
}
__device__ __forceinline__ float bf2f(unsigned short u) {
    union { unsigned u; float f; } v; v.u = ((unsigned)u) << 16; return v.f;
}
__device__ __forceinline__ float softplus_(float a) {
    return (a > 15.f) ? a : __logf(1.f + __expf(a));
}
__device__ __forceinline__ void wait_flag(int* f, int target) {
    if (threadIdx.x == 0) {
        while (__hip_atomic_load(f, __ATOMIC_ACQUIRE, __HIP_MEMORY_SCOPE_AGENT) < target)
            __builtin_amdgcn_s_sleep(2);
    }
    __syncthreads();
}
__device__ __forceinline__ void post_flag(int* f) {
    __threadfence();
    __syncthreads();
    if (threadIdx.x == 0)
        __hip_atomic_fetch_add(f, 1, __ATOMIC_RELEASE, __HIP_MEMORY_SCOPE_AGENT);
}

// ================= K1: front — fused [cvt+GEMM+conv+SiLU] | zlast | Wx cvt =================
// blocks 0..1023: gemm+conv (m = bid>>3, n = bid&7); 1024..1151: zlast; 1152..1175: Wx cvt.
__global__ __launch_bounds__(256) void k_front(const float* __restrict__ x,
                                               const float* __restrict__ Win,
                                               const float* __restrict__ cw,
                                               const float* __restrict__ cb,
                                               const float* __restrict__ Wx,
                                               unsigned short* __restrict__ xsb,
                                               float* __restrict__ zl,
                                               unsigned short* __restrict__ wxb,
                                               int* __restrict__ flags) {
    const int bid = blockIdx.x;
    const int tid = threadIdx.x;
    if (bid < 1024) {
        __shared__ __align__(16) char smem[39168];   // As 80x136 bf16 | Bs 64x136 bf16
        unsigned short (*As)[136] = (unsigned short (*)[136])smem;
        unsigned short (*Bs)[136] = (unsigned short (*)[136])(smem + 21760);
        float (*xiL)[68] = (float (*)[68])smem;      // aliases As after compute

        const int m0 = (bid >> 3) * 64, n0 = (bid & 7) * 64;
        const int lane = tid & 63, wid = tid >> 6;
        const int quad = lane >> 4, l15 = lane & 15;

        f4v acc[4] = {{0,0,0,0},{0,0,0,0},{0,0,0,0},{0,0,0,0}};
        f4v hacc = {0,0,0,0};   // halo: wave w covers n-subtile w

        for (int kh = 0; kh < DM; kh += 128) {
            __syncthreads();
#pragma unroll
            for (int i = tid; i < 80*32; i += 256) {   // A rows m0-16..m0+63 (clamped)
                int r = i >> 5, c4 = (i & 31) << 2;
                int gr = m0 - 16 + r; if (gr < 0) gr = 0;
                float4 v = *(const float4*)(x + (size_t)gr * DM + kh + c4);
                ushort4 o = { rne_bf16(v.x), rne_bf16(v.y), rne_bf16(v.z), rne_bf16(v.w) };
                *(ushort4*)&As[r][c4] = o;
            }
#pragma unroll
            for (int i = tid; i < 64*32; i += 256) {   // B rows n0..n0+63
                int r = i >> 5, c4 = (i & 31) << 2;
                float4 v = *(const float4*)(Win + (size_t)(n0 + r) * DM + kh + c4);
                ushort4 o = { rne_bf16(v.x), rne_bf16(v.y), rne_bf16(v.z), rne_bf16(v.w) };
                *(ushort4*)&Bs[r][c4] = o;
            }
            __syncthreads();
#pragma unroll
            for (int ks = 0; ks < 128; ks += 32) {
                s8v a = *(const s8v*)&As[16 + (wid<<4) + l15][ks + quad*8];
#pragma unroll
                for (int nt = 0; nt < 4; ++nt) {
                    s8v b = *(const s8v*)&Bs[(nt<<4) + l15][ks + quad*8];
                    acc[nt] = __builtin_amdgcn_mfma_f32_16x16x32_bf16(a, b, acc[nt], 0, 0, 0);
                }
                {   // halo: 16 rows x 64 cols spread as 1 n-subtile per wave
                    s8v ah = *(const s8v*)&As[l15][ks + quad*8];
                    s8v b  = *(const s8v*)&Bs[(wid<<4) + l15][ks + quad*8];
                    hacc = __builtin_amdgcn_mfma_f32_16x16x32_bf16(ah, b, hacc, 0, 0, 0);
                }
            }
        }
        __syncthreads();   // done with As/Bs; reuse as xiL
        {
            const int rb = 16 + (wid<<4) + (quad<<2);
#pragma unroll
            for (int nt = 0; nt < 4; ++nt)
#pragma unroll
                for (int r = 0; r < 4; ++r)
                    xiL[rb + r][(nt<<4) + l15] = acc[nt][r];
#pragma unroll
            for (int r = 0; r < 4; ++r)
                xiL[(quad<<2) + r][(wid<<4) + l15] = hacc[r];
        }
        __syncthreads();
        // conv + silu from LDS xi tile: thread -> col c, 16 rows; bf16 output only
        {
            const int c = tid & 63, rg = tid >> 6;
            const int d = n0 + c;
            float4 w = *(const float4*)(cw + d*4);
            const float wk[4] = {w.x, w.y, w.z, w.w};
            float bias = cb[d];
#pragma unroll
            for (int rr = 0; rr < 16; ++rr) {
                int orow = (rg << 4) + rr;        // 0..63
                int Lr = 16 + orow;
                int l = (m0 + orow) & (LL-1);
                float a = bias;
                if (l >= 3) {
                    a = fmaf(wk[0], xiL[Lr-3][c], a);
                    a = fmaf(wk[1], xiL[Lr-2][c], a);
                    a = fmaf(wk[2], xiL[Lr-1][c], a);
                    a = fmaf(wk[3], xiL[Lr  ][c], a);
                } else {
#pragma unroll
                    for (int k = 0; k < 4; ++k) {
                        int lt = l - 3 + k;
                        if (lt >= 0) a = fmaf(wk[k], xiL[Lr-3+k][c], a);
                    }
                }
                float v = a * sig_(a);
                xsb[(size_t)(m0 + orow) * DI + d] = rne_bf16(v);
            }
        }
    } else if (bid < 1152) {
        if (bid == 1024 && tid < 4) flags[tid] = 0;   // reset tail sync flags every call
        int sub = tid & 15;
        int idx = (bid - 1024) * 16 + (tid >> 4);     // 0..2047
        int b = idx >> 9, d = idx & (DI-1);
        const float* xr = x + (size_t)(b*LL + LL-1) * DM + sub*16;
        const float* wr = Win + (size_t)(DI + d) * DM + sub*16;
        float acc = 0.f;
#pragma unroll
        for (int k = 0; k < 16; k += 4)
            acc = dot4(*(const float4*)(xr+k), *(const float4*)(wr+k), acc);
        acc += __shfl_xor(acc, 1); acc += __shfl_xor(acc, 2);
        acc += __shfl_xor(acc, 4); acc += __shfl_xor(acc, 8);
        if (sub == 0) zl[idx] = acc;
    } else {
        int i = (bid - 1152) * 256 + tid;             // 0..6143 quads of Wx
        float4 v = ((const float4*)Wx)[i];
        ushort4 o = { rne_bf16(v.x), rne_bf16(v.y), rne_bf16(v.z), rne_bf16(v.w) };
        ((ushort4*)wxb)[i] = o;
    }
}

// ================= K2: proj = xs @ W_xproj^T via bf16 MFMA (whole Wx in LDS) =================
__global__ __launch_bounds__(256) void k_proj_mfma(const unsigned short* __restrict__ xsb,
                                                   const unsigned short* __restrict__ wxb,
                                                   float* __restrict__ proj) {
    __shared__ unsigned short Bs[48][520];
    __shared__ unsigned short As[64][136];
    const int tid = threadIdx.x;
    const int m0 = blockIdx.x * 64;
    const int lane = tid & 63, wid = tid >> 6;
    const int nrow = lane & 15;
    const int quad = lane >> 4;
#pragma unroll
    for (int i = tid; i < 3072; i += 256) {
        int e = i >> 6, c8 = (i & 63) << 3;
        *(uint4*)&Bs[e][c8] = *(const uint4*)(wxb + (size_t)e*DI + c8);
    }
    f4v acc[3] = {{0,0,0,0},{0,0,0,0},{0,0,0,0}};
    for (int kh = 0; kh < DI; kh += 128) {
        __syncthreads();
#pragma unroll
        for (int i = tid; i < 1024; i += 256) {
            int r = i >> 4, c8 = (i & 15) << 3;
            *(uint4*)&As[r][c8] = *(const uint4*)(xsb + (size_t)(m0+r)*DI + kh + c8);
        }
        __syncthreads();
#pragma unroll
        for (int ks = 0; ks < 128; ks += 32) {
            s8v a = *(const s8v*)&As[(wid<<4) + nrow][ks + quad*8];
#pragma unroll
            for (int nt = 0; nt < 3; ++nt) {
                s8v b = *(const s8v*)&Bs[(nt<<4) + nrow][kh + ks + quad*8];
                acc[nt] = __builtin_amdgcn_mfma_f32_16x16x32_bf16(a, b, acc[nt], 0, 0, 0);
            }
        }
    }
    const int rb = m0 + (wid<<4) + (quad<<2);
#pragma unroll
    for (int nt = 0; nt < 3; ++nt)
#pragma unroll
        for (int r = 0; r < 4; ++r)
            proj[(size_t)(rb + r)*48 + (nt<<4) + nrow] = acc[nt][r];
}

// ================= K3: scan1 with inline dt — thread per (b,c,d), s in regs =================
// hc layout [b][s][c][d]; Dsum [b][c][d]
__global__ __launch_bounds__(256) void k_scan1(const unsigned short* __restrict__ xsb,
                                               const float* __restrict__ proj,
                                               const float* __restrict__ Wdt,
                                               const float* __restrict__ bdt,
                                               const float* __restrict__ Alog,
                                               float* __restrict__ hc,
                                               float* __restrict__ Dsum) {
    int g = blockIdx.x * 256 + threadIdx.x;   // BB*NC*DI = 131072
    int d = g & (DI-1);
    int c = (g >> 9) & (NC-1);
    int b = g >> 15;
    float wdt[16];
#pragma unroll
    for (int e = 0; e < 16; e += 4) {
        float4 v = *(const float4*)(Wdt + d*16 + e);
        wdt[e]=v.x; wdt[e+1]=v.y; wdt[e+2]=v.z; wdt[e+3]=v.w;
    }
    float bd = bdt[d];
    float Af[16];
#pragma unroll
    for (int s4 = 0; s4 < 16; s4 += 4) {
        float4 al = *(const float4*)(Alog + d*16 + s4);
        Af[s4+0] = -__expf(al.x); Af[s4+1] = -__expf(al.y);
        Af[s4+2] = -__expf(al.z); Af[s4+3] = -__expf(al.w);
    }
    float h[16];
#pragma unroll
    for (int s = 0; s < 16; ++s) h[s] = 0.f;
    float Dl = 0.f;
    int rbase = b*LL + c*CK;
    for (int i = 0; i < CK; ++i) {
        int r = rbase + i;
        const float* pr = proj + (size_t)r*48;          // wave-uniform -> scalar loads
        float a = bd;
#pragma unroll
        for (int e = 0; e < 16; ++e) a = fmaf(pr[e], wdt[e], a);
        float dtv = softplus_(a);
        float xsv = bf2f(xsb[(size_t)r*DI + d]);        // coalesced bf16
        float u = dtv * xsv;
        Dl += dtv;
#pragma unroll
        for (int s = 0; s < 16; ++s)
            h[s] = fmaf(__expf(dtv * Af[s]), h[s], u * pr[16+s]);
    }
#pragma unroll
    for (int s = 0; s < 16; ++s)
        hc[((size_t)((b*16 + s)*NC + c) << 9) + d] = h[s];
    Dsum[((size_t)(b*NC + c) << 9) + d] = Dl;
}

// ================= K4: tail — scan2(blk 0..7) -> mout(8..71) -> lstm(72..583) =================
__global__ __launch_bounds__(256) void k_tail(const float* __restrict__ hc,
                                              const float* __restrict__ Dsum,
                                              const float* __restrict__ Alog,
                                              const float* __restrict__ proj,
                                              const unsigned short* __restrict__ xsb,
                                              const float* __restrict__ Dp,
                                              const float* __restrict__ zl,
                                              const float* __restrict__ Wout,
                                              const float* __restrict__ m_h0,
                                              const float* __restrict__ c0,
                                              const float* __restrict__ Wih,
                                              const float* __restrict__ Whh,
                                              const float* __restrict__ bih,
                                              const float* __restrict__ bhh,
                                              float* __restrict__ ypre,
                                              float* __restrict__ mm,
                                              int* __restrict__ flags,
                                              float* __restrict__ out) {
    const int bid = blockIdx.x;
    const int tid = threadIdx.x;
    if (bid < 8) {
        // ---- scan2: cross-chunk combine + epilogue; thread per (b,d) ----
        int b = bid >> 1;
        int d = ((bid & 1) << 8) + tid;   // 0..511
        float Af[16];
#pragma unroll
        for (int s4 = 0; s4 < 16; s4 += 4) {
            float4 al = *(const float4*)(Alog + d*16 + s4);
            Af[s4+0] = -__expf(al.x); Af[s4+1] = -__expf(al.y);
            Af[s4+2] = -__expf(al.z); Af[s4+3] = -__expf(al.w);
        }
        float h[16];
#pragma unroll
        for (int s = 0; s < 16; ++s) h[s] = 0.f;
        float Ss = 0.f;
        const float* hcb = hc + ((size_t)(b*16*NC) << 9) + d;
        const float* Db  = Dsum + ((size_t)(b*NC) << 9) + d;
        for (int c = NC-1; c >= 0; --c) {
            float Dc = Db[(size_t)c << 9];
#pragma unroll
            for (int s = 0; s < 16; ++s)
                h[s] = fmaf(__expf(Af[s] * Ss), hcb[((size_t)(s*NC + c)) << 9], h[s]);
            Ss += Dc;
        }
        int rlast = b*LL + LL - 1;
        const float* pr = proj + (size_t)rlast*48 + 32;
        float y = 0.f;
#pragma unroll
        for (int s = 0; s < 16; ++s) y = fmaf(h[s], pr[s], y);
        y += bf2f(xsb[(size_t)rlast*DI + d]) * Dp[d];
        float z = zl[b*DI + d];
        y *= z * sig_(z);
        ypre[b*DI + d] = y;
        post_flag(&flags[0]);
    } else if (bid < 72) {
        // ---- mout: m = y_pre @ W_out^T ----
        wait_flag(&flags[0], 8);
        __threadfence();
        int sub = tid & 15;
        int idx = (bid - 8) * 16 + (tid >> 4);   // 0..1023
        int b = idx >> 8, o = idx & 255;
        const float* yr = ypre + b * DI + sub*32;
        const float* wr = Wout + (size_t)o * DI + sub*32;
        float acc = 0.f;
#pragma unroll
        for (int k = 0; k < 32; k += 4)
            acc = dot4(*(const float4*)(yr+k), *(const float4*)(wr+k), acc);
        acc += __shfl_xor(acc, 1); acc += __shfl_xor(acc, 2);
        acc += __shfl_xor(acc, 4); acc += __shfl_xor(acc, 8);
        if (sub == 0) mm[idx] = acc;
        post_flag(&flags[1]);
    } else {
        // ---- lstm: one wave per (b,j) ----
        wait_flag(&flags[1], 64);
        __threadfence();
        int lane = tid & 63;
        int wid  = tid >> 6;
        int p = (bid - 72) * 4 + wid;     // 0..2047
        int b = p >> 9, j = p & (HIDN-1);
        int q = lane >> 4, sub = lane & 15;
        int jj = q * HIDN + j;
        float acc = 0.f;
        {
            const float* wi = Wih + (size_t)jj * DM + sub*16;
            const float* mr = mm + b * DM + sub*16;
#pragma unroll
            for (int k = 0; k < 16; k += 4)
                acc = dot4(*(const float4*)(mr+k), *(const float4*)(wi+k), acc);
        }
        {
            const float* wh = Whh + (size_t)jj * HIDN + sub*32;
            const float* hr = m_h0 + b * HIDN + sub*32;
#pragma unroll
            for (int k = 0; k < 32; k += 4)
                acc = dot4(*(const float4*)(hr+k), *(const float4*)(wh+k), acc);
        }
        if (sub == 0) acc += bih[jj] + bhh[jj];
        acc += __shfl_xor(acc, 1); acc += __shfl_xor(acc, 2);
        acc += __shfl_xor(acc, 4); acc += __shfl_xor(acc, 8);
        float gi = __shfl(acc, 0);
        float gf = __shfl(acc, 16);
        float gg = __shfl(acc, 32);
        float go = __shfl(acc, 48);
        if (lane == 0) {
            int idx = b * HIDN + j;
            float cn = sig_(gf) * c0[idx] + sig_(gi) * tanhf(gg);
            float hn = sig_(go) * tanhf(cn);
            out[idx] = hn;                 // h_new
            out[BB*HIDN + idx] = cn;       // c_new
        }
    }
}

extern "C" void kernel_launch(void* const* d_in, const int* in_sizes, int n_in,
                              void* d_out, int out_size, void* d_ws, size_t ws_size,
                              hipStream_t stream) {
    const float* x     = (const float*)d_in[0];
    const float* h0    = (const float*)d_in[1];
    const float* c0    = (const float*)d_in[2];
    const float* Win   = (const float*)d_in[3];
    const float* convw = (const float*)d_in[4];
    const float* convb = (const float*)d_in[5];
    const float* Wx    = (const float*)d_in[6];
    const float* Wdt   = (const float*)d_in[7];
    const float* bdt   = (const float*)d_in[8];
    const float* Alog  = (const float*)d_in[9];
    const float* Dp    = (const float*)d_in[10];
    const float* Wout  = (const float*)d_in[11];
    const float* Wih   = (const float*)d_in[12];
    const float* Whh   = (const float*)d_in[13];
    const float* bih   = (const float*)d_in[14];
    const float* bhh   = (const float*)d_in[15];

    float* ws   = (float*)d_ws;
    float* proj = ws;                          // ROWS*48
    float* hc   = proj + (size_t)ROWS*48;      // BB*16*NC*DI  [b][s][c][d]
    float* Dsum = hc + (size_t)BB*DSN*NC*DI;   // BB*NC*DI     [b][c][d]
    float* zl   = Dsum + (size_t)BB*NC*DI;     // BB*DI
    float* ypre = zl + (size_t)BB*DI;          // BB*DI
    float* mm   = ypre + (size_t)BB*DI;        // BB*DM
    int*   flags = (int*)(mm + (size_t)BB*DM); // 4 ints
    unsigned short* wxb = (unsigned short*)(flags + 4);  // 48*DI bf16
    unsigned short* xsb = wxb + (size_t)48*DI;           // ROWS*DI bf16
    float* out  = (float*)d_out;

    k_front    <<<1176, 256, 0, stream>>>(x, Win, convw, convb, Wx, xsb, zl, wxb, flags);
    k_proj_mfma<<<ROWS/64, 256, 0, stream>>>(xsb, wxb, proj);
    k_scan1    <<<BB*NC*DI/256, 256, 0, stream>>>(xsb, proj, Wdt, bdt, Alog, hc, Dsum);
    k_tail     <<<584, 256, 0, stream>>>(hc, Dsum, Alog, proj, xsb, Dp, zl, Wout,
                                         h0, c0, Wih, Whh, bih, bhh, ypre, mm, flags, out);
}

// Round 9
// 191.691 us; speedup vs baseline: 2.7568x; 2.7568x over previous
//
#include <hip/hip_runtime.h>
#include <math.h>

#define BB   4
#define LL   2048
#define DM   256
#define DI   512
#define DSN  16
#define HIDN 512
#define NC   64
#define CK   32           // LL / NC
#define ROWS (BB*LL)      // 8192

typedef __attribute__((ext_vector_type(8))) short s8v;   // 8 bf16 (4 VGPRs)
typedef __attribute__((ext_vector_type(4))) float f4v;   // 4 fp32 acc

__device__ __forceinline__ float sig_(float x) { return 1.f / (1.f + __expf(-x)); }
__device__ __forceinline__ float dot4(float4 a, float4 w, float acc) {
    return fmaf(a.x,w.x, fmaf(a.y,w.y, fmaf(a.z,w.z, fmaf(a.w,w.w, acc))));
}
__device__ __forceinline__ unsigned short rne_bf16(float f) {
    union { float f; unsigned u; } v; v.f = f;
    unsigned r = v.u + 0x7FFFu + ((v.u >> 16) & 1u);
    return (unsigned short)(r >> 16);
}
__device__ __forceinline__ float bf2f(unsigned short u) {
    union { unsigned u; float f; } v; v.u = ((unsigned)u) << 16; return v.f;
}
__device__ __forceinline__ float softplus_(float a) {
    return (a > 15.f) ? a : __logf(1.f + __expf(a));
}

// ================= K1: front — fused [cvt+GEMM+conv+SiLU] | zlast | Wx cvt =================
// blocks 0..1023: gemm+conv (m = bid>>3, n = bid&7); 1024..1151: zlast; 1152..1175: Wx cvt.
__global__ __launch_bounds__(256) void k_front(const float* __restrict__ x,
                                               const float* __restrict__ Win,
                                               const float* __restrict__ cw,
                                               const float* __restrict__ cb,
                                               const float* __restrict__ Wx,
                                               unsigned short* __restrict__ xsb,
                                               float* __restrict__ zl,
                                               unsigned short* __restrict__ wxb) {
    const int bid = blockIdx.x;
    const int tid = threadIdx.x;
    if (bid < 1024) {
        __shared__ __align__(16) char smem[39168];   // As 80x136 bf16 | Bs 64x136 bf16
        unsigned short (*As)[136] = (unsigned short (*)[136])smem;
        unsigned short (*Bs)[136] = (unsigned short (*)[136])(smem + 21760);
        float (*xiL)[68] = (float (*)[68])smem;      // aliases As after compute

        const int m0 = (bid >> 3) * 64, n0 = (bid & 7) * 64;
        const int lane = tid & 63, wid = tid >> 6;
        const int quad = lane >> 4, l15 = lane & 15;

        f4v acc[4] = {{0,0,0,0},{0,0,0,0},{0,0,0,0},{0,0,0,0}};
        f4v hacc = {0,0,0,0};   // halo: wave w covers n-subtile w

        for (int kh = 0; kh < DM; kh += 128) {
            __syncthreads();
#pragma unroll
            for (int i = tid; i < 80*32; i += 256) {   // A rows m0-16..m0+63 (clamped)
                int r = i >> 5, c4 = (i & 31) << 2;
                int gr = m0 - 16 + r; if (gr < 0) gr = 0;
                float4 v = *(const float4*)(x + (size_t)gr * DM + kh + c4);
                ushort4 o = { rne_bf16(v.x), rne_bf16(v.y), rne_bf16(v.z), rne_bf16(v.w) };
                *(ushort4*)&As[r][c4] = o;
            }
#pragma unroll
            for (int i = tid; i < 64*32; i += 256) {   // B rows n0..n0+63
                int r = i >> 5, c4 = (i & 31) << 2;
                float4 v = *(const float4*)(Win + (size_t)(n0 + r) * DM + kh + c4);
                ushort4 o = { rne_bf16(v.x), rne_bf16(v.y), rne_bf16(v.z), rne_bf16(v.w) };
                *(ushort4*)&Bs[r][c4] = o;
            }
            __syncthreads();
#pragma unroll
            for (int ks = 0; ks < 128; ks += 32) {
                s8v a = *(const s8v*)&As[16 + (wid<<4) + l15][ks + quad*8];
#pragma unroll
                for (int nt = 0; nt < 4; ++nt) {
                    s8v b = *(const s8v*)&Bs[(nt<<4) + l15][ks + quad*8];
                    acc[nt] = __builtin_amdgcn_mfma_f32_16x16x32_bf16(a, b, acc[nt], 0, 0, 0);
                }
                {   // halo: 16 rows x 64 cols spread as 1 n-subtile per wave
                    s8v ah = *(const s8v*)&As[l15][ks + quad*8];
                    s8v b  = *(const s8v*)&Bs[(wid<<4) + l15][ks + quad*8];
                    hacc = __builtin_amdgcn_mfma_f32_16x16x32_bf16(ah, b, hacc, 0, 0, 0);
                }
            }
        }
        __syncthreads();   // done with As/Bs; reuse as xiL
        {
            const int rb = 16 + (wid<<4) + (quad<<2);
#pragma unroll
            for (int nt = 0; nt < 4; ++nt)
#pragma unroll
                for (int r = 0; r < 4; ++r)
                    xiL[rb + r][(nt<<4) + l15] = acc[nt][r];
#pragma unroll
            for (int r = 0; r < 4; ++r)
                xiL[(quad<<2) + r][(wid<<4) + l15] = hacc[r];
        }
        __syncthreads();
        // conv + silu from LDS xi tile: thread -> col c, 16 rows; bf16 output only
        {
            const int c = tid & 63, rg = tid >> 6;
            const int d = n0 + c;
            float4 w = *(const float4*)(cw + d*4);
            const float wk[4] = {w.x, w.y, w.z, w.w};
            float bias = cb[d];
#pragma unroll
            for (int rr = 0; rr < 16; ++rr) {
                int orow = (rg << 4) + rr;        // 0..63
                int Lr = 16 + orow;
                int l = (m0 + orow) & (LL-1);
                float a = bias;
                if (l >= 3) {
                    a = fmaf(wk[0], xiL[Lr-3][c], a);
                    a = fmaf(wk[1], xiL[Lr-2][c], a);
                    a = fmaf(wk[2], xiL[Lr-1][c], a);
                    a = fmaf(wk[3], xiL[Lr  ][c], a);
                } else {
#pragma unroll
                    for (int k = 0; k < 4; ++k) {
                        int lt = l - 3 + k;
                        if (lt >= 0) a = fmaf(wk[k], xiL[Lr-3+k][c], a);
                    }
                }
                float v = a * sig_(a);
                xsb[(size_t)(m0 + orow) * DI + d] = rne_bf16(v);
            }
        }
    } else if (bid < 1152) {
        int sub = tid & 15;
        int idx = (bid - 1024) * 16 + (tid >> 4);     // 0..2047
        int b = idx >> 9, d = idx & (DI-1);
        const float* xr = x + (size_t)(b*LL + LL-1) * DM + sub*16;
        const float* wr = Win + (size_t)(DI + d) * DM + sub*16;
        float acc = 0.f;
#pragma unroll
        for (int k = 0; k < 16; k += 4)
            acc = dot4(*(const float4*)(xr+k), *(const float4*)(wr+k), acc);
        acc += __shfl_xor(acc, 1); acc += __shfl_xor(acc, 2);
        acc += __shfl_xor(acc, 4); acc += __shfl_xor(acc, 8);
        if (sub == 0) zl[idx] = acc;
    } else {
        int i = (bid - 1152) * 256 + tid;             // 0..6143 quads of Wx
        float4 v = ((const float4*)Wx)[i];
        ushort4 o = { rne_bf16(v.x), rne_bf16(v.y), rne_bf16(v.z), rne_bf16(v.w) };
        ((ushort4*)wxb)[i] = o;
    }
}

// ================= K2: proj = xs @ W_xproj^T via bf16 MFMA (whole Wx in LDS) =================
__global__ __launch_bounds__(256) void k_proj_mfma(const unsigned short* __restrict__ xsb,
                                                   const unsigned short* __restrict__ wxb,
                                                   float* __restrict__ proj) {
    __shared__ unsigned short Bs[48][520];
    __shared__ unsigned short As[64][136];
    const int tid = threadIdx.x;
    const int m0 = blockIdx.x * 64;
    const int lane = tid & 63, wid = tid >> 6;
    const int nrow = lane & 15;
    const int quad = lane >> 4;
#pragma unroll
    for (int i = tid; i < 3072; i += 256) {
        int e = i >> 6, c8 = (i & 63) << 3;
        *(uint4*)&Bs[e][c8] = *(const uint4*)(wxb + (size_t)e*DI + c8);
    }
    f4v acc[3] = {{0,0,0,0},{0,0,0,0},{0,0,0,0}};
    for (int kh = 0; kh < DI; kh += 128) {
        __syncthreads();
#pragma unroll
        for (int i = tid; i < 1024; i += 256) {
            int r = i >> 4, c8 = (i & 15) << 3;
            *(uint4*)&As[r][c8] = *(const uint4*)(xsb + (size_t)(m0+r)*DI + kh + c8);
        }
        __syncthreads();
#pragma unroll
        for (int ks = 0; ks < 128; ks += 32) {
            s8v a = *(const s8v*)&As[(wid<<4) + nrow][ks + quad*8];
#pragma unroll
            for (int nt = 0; nt < 3; ++nt) {
                s8v b = *(const s8v*)&Bs[(nt<<4) + nrow][kh + ks + quad*8];
                acc[nt] = __builtin_amdgcn_mfma_f32_16x16x32_bf16(a, b, acc[nt], 0, 0, 0);
            }
        }
    }
    const int rb = m0 + (wid<<4) + (quad<<2);
#pragma unroll
    for (int nt = 0; nt < 3; ++nt)
#pragma unroll
        for (int r = 0; r < 4; ++r)
            proj[(size_t)(rb + r)*48 + (nt<<4) + nrow] = acc[nt][r];
}

// ================= K3: scan1 with inline dt — thread per (b,c,d), s in regs =================
// hc layout [b][s][c][d]; Dsum [b][c][d]
__global__ __launch_bounds__(256) void k_scan1(const unsigned short* __restrict__ xsb,
                                               const float* __restrict__ proj,
                                               const float* __restrict__ Wdt,
                                               const float* __restrict__ bdt,
                                               const float* __restrict__ Alog,
                                               float* __restrict__ hc,
                                               float* __restrict__ Dsum) {
    int g = blockIdx.x * 256 + threadIdx.x;   // BB*NC*DI = 131072
    int d = g & (DI-1);
    int c = (g >> 9) & (NC-1);
    int b = g >> 15;
    float wdt[16];
#pragma unroll
    for (int e = 0; e < 16; e += 4) {
        float4 v = *(const float4*)(Wdt + d*16 + e);
        wdt[e]=v.x; wdt[e+1]=v.y; wdt[e+2]=v.z; wdt[e+3]=v.w;
    }
    float bd = bdt[d];
    float Af[16];
#pragma unroll
    for (int s4 = 0; s4 < 16; s4 += 4) {
        float4 al = *(const float4*)(Alog + d*16 + s4);
        Af[s4+0] = -__expf(al.x); Af[s4+1] = -__expf(al.y);
        Af[s4+2] = -__expf(al.z); Af[s4+3] = -__expf(al.w);
    }
    float h[16];
#pragma unroll
    for (int s = 0; s < 16; ++s) h[s] = 0.f;
    float Dl = 0.f;
    int rbase = b*LL + c*CK;
    for (int i = 0; i < CK; ++i) {
        int r = rbase + i;
        const float* pr = proj + (size_t)r*48;          // wave-uniform -> scalar loads
        float a = bd;
#pragma unroll
        for (int e = 0; e < 16; ++e) a = fmaf(pr[e], wdt[e], a);
        float dtv = softplus_(a);
        float xsv = bf2f(xsb[(size_t)r*DI + d]);        // coalesced bf16
        float u = dtv * xsv;
        Dl += dtv;
#pragma unroll
        for (int s = 0; s < 16; ++s)
            h[s] = fmaf(__expf(dtv * Af[s]), h[s], u * pr[16+s]);
    }
#pragma unroll
    for (int s = 0; s < 16; ++s)
        hc[((size_t)((b*16 + s)*NC + c) << 9) + d] = h[s];
    Dsum[((size_t)(b*NC + c) << 9) + d] = Dl;
}

// ================= K4: scan2 — thread per (b,d), s in regs, fused epilogue =================
__global__ __launch_bounds__(256) void k_scan2(const float* __restrict__ hc,
                                               const float* __restrict__ Dsum,
                                               const float* __restrict__ Alog,
                                               const float* __restrict__ proj,
                                               const unsigned short* __restrict__ xsb,
                                               const float* __restrict__ Dp,
                                               const float* __restrict__ zl,
                                               float* __restrict__ ypre) {
    int b = blockIdx.x >> 1;
    int d = ((blockIdx.x & 1) << 8) + threadIdx.x;   // 0..511
    float Af[16];
#pragma unroll
    for (int s4 = 0; s4 < 16; s4 += 4) {
        float4 al = *(const float4*)(Alog + d*16 + s4);
        Af[s4+0] = -__expf(al.x); Af[s4+1] = -__expf(al.y);
        Af[s4+2] = -__expf(al.z); Af[s4+3] = -__expf(al.w);
    }
    float h[16];
#pragma unroll
    for (int s = 0; s < 16; ++s) h[s] = 0.f;
    float Ss = 0.f;
    const float* hcb = hc + ((size_t)(b*16*NC) << 9) + d;
    const float* Db  = Dsum + ((size_t)(b*NC) << 9) + d;
    for (int c = NC-1; c >= 0; --c) {
        float Dc = Db[(size_t)c << 9];
#pragma unroll
        for (int s = 0; s < 16; ++s)
            h[s] = fmaf(__expf(Af[s] * Ss), hcb[((size_t)(s*NC + c)) << 9], h[s]);
        Ss += Dc;
    }
    int rlast = b*LL + LL - 1;
    const float* pr = proj + (size_t)rlast*48 + 32;   // wave-uniform
    float y = 0.f;
#pragma unroll
    for (int s = 0; s < 16; ++s) y = fmaf(h[s], pr[s], y);
    y += bf2f(xsb[(size_t)rlast*DI + d]) * Dp[d];
    float z = zl[b*DI + d];
    y *= z * sig_(z);
    ypre[b*DI + d] = y;
}

// ================= K5: m = y_pre @ W_out^T  (4 x 256, K=512) =================
__global__ __launch_bounds__(256) void k_mout(const float* __restrict__ ypre,
                                              const float* __restrict__ Wout,
                                              float* __restrict__ m) {
    int sub = threadIdx.x & 15;
    int idx = blockIdx.x * 16 + (threadIdx.x >> 4);   // 0..1023
    int b = idx >> 8, o = idx & 255;
    const float* yr = ypre + b * DI + sub*32;
    const float* wr = Wout + (size_t)o * DI + sub*32;
    float acc = 0.f;
#pragma unroll
    for (int k = 0; k < 32; k += 4)
        acc = dot4(*(const float4*)(yr+k), *(const float4*)(wr+k), acc);
    acc += __shfl_xor(acc, 1); acc += __shfl_xor(acc, 2);
    acc += __shfl_xor(acc, 4); acc += __shfl_xor(acc, 8);
    if (sub == 0) m[idx] = acc;
}

// ================= K6: LSTM cell — one wave per (b,j) =================
__global__ __launch_bounds__(256) void k_lstm(const float* __restrict__ m,
                                              const float* __restrict__ h0,
                                              const float* __restrict__ c0,
                                              const float* __restrict__ Wih,
                                              const float* __restrict__ Whh,
                                              const float* __restrict__ bih,
                                              const float* __restrict__ bhh,
                                              float* __restrict__ out) {
    int lane = threadIdx.x & 63;
    int wid  = threadIdx.x >> 6;
    int p = blockIdx.x * 4 + wid;     // 0..2047
    int b = p >> 9, j = p & (HIDN-1);
    int q = lane >> 4, sub = lane & 15;
    int jj = q * HIDN + j;
    float acc = 0.f;
    {
        const float* wi = Wih + (size_t)jj * DM + sub*16;
        const float* mr = m + b * DM + sub*16;
#pragma unroll
        for (int k = 0; k < 16; k += 4)
            acc = dot4(*(const float4*)(mr+k), *(const float4*)(wi+k), acc);
    }
    {
        const float* wh = Whh + (size_t)jj * HIDN + sub*32;
        const float* hr = h0 + b * HIDN + sub*32;
#pragma unroll
        for (int k = 0; k < 32; k += 4)
            acc = dot4(*(const float4*)(hr+k), *(const float4*)(wh+k), acc);
    }
    if (sub == 0) acc += bih[jj] + bhh[jj];
    acc += __shfl_xor(acc, 1); acc += __shfl_xor(acc, 2);
    acc += __shfl_xor(acc, 4); acc += __shfl_xor(acc, 8);
    float gi = __shfl(acc, 0);
    float gf = __shfl(acc, 16);
    float gg = __shfl(acc, 32);
    float go = __shfl(acc, 48);
    if (lane == 0) {
        int idx = b * HIDN + j;
        float cn = sig_(gf) * c0[idx] + sig_(gi) * tanhf(gg);
        float hn = sig_(go) * tanhf(cn);
        out[idx] = hn;                 // h_new
        out[BB*HIDN + idx] = cn;       // c_new
    }
}

extern "C" void kernel_launch(void* const* d_in, const int* in_sizes, int n_in,
                              void* d_out, int out_size, void* d_ws, size_t ws_size,
                              hipStream_t stream) {
    const float* x     = (const float*)d_in[0];
    const float* h0    = (const float*)d_in[1];
    const float* c0    = (const float*)d_in[2];
    const float* Win   = (const float*)d_in[3];
    const float* convw = (const float*)d_in[4];
    const float* convb = (const float*)d_in[5];
    const float* Wx    = (const float*)d_in[6];
    const float* Wdt   = (const float*)d_in[7];
    const float* bdt   = (const float*)d_in[8];
    const float* Alog  = (const float*)d_in[9];
    const float* Dp    = (const float*)d_in[10];
    const float* Wout  = (const float*)d_in[11];
    const float* Wih   = (const float*)d_in[12];
    const float* Whh   = (const float*)d_in[13];
    const float* bih   = (const float*)d_in[14];
    const float* bhh   = (const float*)d_in[15];

    float* ws   = (float*)d_ws;
    float* proj = ws;                          // ROWS*48
    float* hc   = proj + (size_t)ROWS*48;      // BB*16*NC*DI  [b][s][c][d]
    float* Dsum = hc + (size_t)BB*DSN*NC*DI;   // BB*NC*DI     [b][c][d]
    float* zl   = Dsum + (size_t)BB*NC*DI;     // BB*DI
    float* ypre = zl + (size_t)BB*DI;          // BB*DI
    float* mm   = ypre + (size_t)BB*DI;        // BB*DM
    unsigned short* wxb = (unsigned short*)(mm + (size_t)BB*DM);  // 48*DI bf16
    unsigned short* xsb = wxb + (size_t)48*DI;                    // ROWS*DI bf16
    float* out  = (float*)d_out;

    k_front    <<<1176, 256, 0, stream>>>(x, Win, convw, convb, Wx, xsb, zl, wxb);
    k_proj_mfma<<<ROWS/64, 256, 0, stream>>>(xsb, wxb, proj);
    k_scan1    <<<BB*NC*DI/256, 256, 0, stream>>>(xsb, proj, Wdt, bdt, Alog, hc, Dsum);
    k_scan2    <<<8, 256, 0, stream>>>(hc, Dsum, Alog, proj, xsb, Dp, zl, ypre);
    k_mout     <<<BB*DM/16, 256, 0, stream>>>(ypre, Wout, mm);
    k_lstm     <<<BB*HIDN/4, 256, 0, stream>>>(mm, h0, c0, Wih, Whh, bih, bhh, out);
}